// Round 1
// baseline (477.694 us; speedup 1.0000x reference)
//
#include <hip/hip_runtime.h>
#include <math.h>

#define N_NODES  100000
#define N_EDGES  800000
#define F        64
#define N_GRAPHS 64

// ---------------- workspace layout (bytes) ----------------
#define OFF_H    0u           // float[N_NODES*F]   25,600,000
#define OFF_HW   25600000u    // float[N_NODES*F]   25,600,000
#define OFF_DIS  51200000u    // float[N_NODES]        400,000
#define OFF_DEG  51600000u    // int[N_NODES]          400,000
#define OFF_FILL 52000000u    // int[N_NODES]          400,000
#define OFF_ROWP 52400000u    // int[N_NODES+1]        400,004
#define OFF_COL  52800256u    // int[N_EDGES]        3,200,000
#define OFF_BSUM 56000256u    // int[128]
// total ~56.0 MB

__global__ void k_zero(int* __restrict__ p, int n) {
    int i = blockIdx.x * blockDim.x + threadIdx.x;
    if (i < n) p[i] = 0;
}

__global__ void k_degree(const int* __restrict__ dst, int* __restrict__ degcnt) {
    int e = blockIdx.x * blockDim.x + threadIdx.x;
    if (e < N_EDGES) atomicAdd(&degcnt[dst[e]], 1);
}

__global__ void k_dis(const int* __restrict__ degcnt, float* __restrict__ dis) {
    int i = blockIdx.x * blockDim.x + threadIdx.x;
    if (i < N_NODES) dis[i] = rsqrtf((float)degcnt[i] + 1.0f);
}

// block-level inclusive scan of degcnt -> rowptr[i+1]; block totals -> bsum
__global__ void k_scan1(const int* __restrict__ degcnt, int* __restrict__ rowptr,
                        int* __restrict__ bsum) {
    __shared__ int s[1024];
    int i = blockIdx.x * 1024 + threadIdx.x;
    int v = (i < N_NODES) ? degcnt[i] : 0;
    s[threadIdx.x] = v;
    __syncthreads();
    for (int off = 1; off < 1024; off <<= 1) {
        int t = (threadIdx.x >= off) ? s[threadIdx.x - off] : 0;
        __syncthreads();
        s[threadIdx.x] += t;
        __syncthreads();
    }
    if (i < N_NODES) rowptr[i + 1] = s[threadIdx.x];
    if (threadIdx.x == 1023) bsum[blockIdx.x] = s[1023];
}

__global__ void k_scan2(int* __restrict__ bsum, int nb) {
    if (blockIdx.x == 0 && threadIdx.x == 0) {
        int acc = 0;
        for (int b = 0; b < nb; ++b) { int v = bsum[b]; bsum[b] = acc; acc += v; }
    }
}

__global__ void k_scan3(int* __restrict__ rowptr, const int* __restrict__ bsum) {
    int i = blockIdx.x * 1024 + threadIdx.x;
    if (i < N_NODES) rowptr[i + 1] += bsum[blockIdx.x];
    if (i == 0) rowptr[0] = 0;
}

__global__ void k_fill(const int* __restrict__ src, const int* __restrict__ dst,
                       const int* __restrict__ rowptr, int* __restrict__ fillc,
                       int* __restrict__ col) {
    int e = blockIdx.x * blockDim.x + threadIdx.x;
    if (e < N_EDGES) {
        int d = dst[e];
        int pos = rowptr[d] + atomicAdd(&fillc[d], 1);
        col[pos] = src[e];
    }
}

// hw[r][f] = sum_k hin[r][k] * W[k][f]; one wave per row (lane = f),
// W column f kept in 64 VGPRs, h row broadcast via __shfl(readlane).
__global__ __launch_bounds__(256) void k_gemm(const float* __restrict__ hin,
                                              const float* __restrict__ W,
                                              float* __restrict__ hout) {
    int lane = threadIdx.x & 63;
    int wid  = (blockIdx.x * blockDim.x + threadIdx.x) >> 6;
    int nwaves = (gridDim.x * blockDim.x) >> 6;
    float w[F];
#pragma unroll
    for (int k = 0; k < F; ++k) w[k] = W[k * F + lane];   // coalesced per instr
    for (int r = wid; r < N_NODES; r += nwaves) {
        float hv = hin[r * F + lane];
        float acc = 0.f;
#pragma unroll
        for (int k = 0; k < F; ++k) {
            float hk = __shfl(hv, k, 64);
            acc = fmaf(hk, w[k], acc);
        }
        hout[r * F + lane] = acc;
    }
}

// h_out[n] = dis[n]*( sum_{e: dst=n} dis[src]*hw[src] + dis[n]*hw[n] ) + b,
// optional relu.  One wave per node, lane = feature.
template<bool RELU>
__global__ __launch_bounds__(256) void k_agg(const float* __restrict__ hw,
                                             const int* __restrict__ rowptr,
                                             const int* __restrict__ col,
                                             const float* __restrict__ dis,
                                             const float* __restrict__ bias,
                                             float* __restrict__ hout) {
    int lane = threadIdx.x & 63;
    int wid  = (blockIdx.x * blockDim.x + threadIdx.x) >> 6;
    int nwaves = (gridDim.x * blockDim.x) >> 6;
    float bv = bias[lane];
    for (int n = wid; n < N_NODES; n += nwaves) {
        int e0 = rowptr[n], e1 = rowptr[n + 1];
        float dn = dis[n];
        float acc = dn * hw[(size_t)n * F + lane];
        int e = e0;
        for (; e + 3 < e1; e += 4) {          // 4 gathers in flight
            int s0 = col[e], s1 = col[e + 1], s2 = col[e + 2], s3 = col[e + 3];
            float d0 = dis[s0], d1 = dis[s1], d2 = dis[s2], d3 = dis[s3];
            float v0 = hw[(size_t)s0 * F + lane];
            float v1 = hw[(size_t)s1 * F + lane];
            float v2 = hw[(size_t)s2 * F + lane];
            float v3 = hw[(size_t)s3 * F + lane];
            acc = fmaf(d0, v0, acc);
            acc = fmaf(d1, v1, acc);
            acc = fmaf(d2, v2, acc);
            acc = fmaf(d3, v3, acc);
        }
        for (; e < e1; ++e) {
            int s = col[e];
            acc = fmaf(dis[s], hw[(size_t)s * F + lane], acc);
        }
        float res = fmaf(dn, acc, bv);
        if (RELU) res = fmaxf(res, 0.f);
        hout[(size_t)n * F + lane] = res;
    }
}

__global__ void k_pool_init(float* __restrict__ out) {
    int i = blockIdx.x * blockDim.x + threadIdx.x;
    if (i < N_GRAPHS * F) out[i] = -INFINITY;
}

__device__ inline void atomicMaxFloat(float* addr, float v) {
    if (v >= 0.f) atomicMax((int*)addr, __float_as_int(v));
    else          atomicMin((unsigned int*)addr, __float_as_uint(v));
}

// batch is sorted: each wave scans a contiguous node chunk, keeps running max,
// flushes on graph boundary.
__global__ __launch_bounds__(256) void k_pool(const float* __restrict__ h,
                                              const int* __restrict__ batch,
                                              float* __restrict__ out) {
    int lane = threadIdx.x & 63;
    int wid  = (blockIdx.x * blockDim.x + threadIdx.x) >> 6;
    int nwaves = (gridDim.x * blockDim.x) >> 6;
    int per = (N_NODES + nwaves - 1) / nwaves;
    int n0 = wid * per, n1 = min(N_NODES, n0 + per);
    if (n0 >= n1) return;
    float acc = -INFINITY;
    int cur = batch[n0];
    for (int n = n0; n < n1; ++n) {
        int g = batch[n];
        if (g != cur) {
            atomicMaxFloat(&out[cur * F + lane], acc);
            acc = -INFINITY; cur = g;
        }
        acc = fmaxf(acc, h[(size_t)n * F + lane]);
    }
    atomicMaxFloat(&out[cur * F + lane], acc);
}

extern "C" void kernel_launch(void* const* d_in, const int* in_sizes, int n_in,
                              void* d_out, int out_size, void* d_ws, size_t ws_size,
                              hipStream_t stream) {
    const float* x     = (const float*)d_in[0];
    const int*   ei    = (const int*)d_in[1];
    const int*   batch = (const int*)d_in[2];
    const float* W1 = (const float*)d_in[3];
    const float* b1 = (const float*)d_in[4];
    const float* W2 = (const float*)d_in[5];
    const float* b2 = (const float*)d_in[6];
    const float* W3 = (const float*)d_in[7];
    const float* b3 = (const float*)d_in[8];
    const int* src = ei;
    const int* dst = ei + N_EDGES;

    char* ws = (char*)d_ws;
    float* h      = (float*)(ws + OFF_H);
    float* hw     = (float*)(ws + OFF_HW);
    float* dis    = (float*)(ws + OFF_DIS);
    int*   degcnt = (int*)(ws + OFF_DEG);
    int*   fillc  = (int*)(ws + OFF_FILL);
    int*   rowptr = (int*)(ws + OFF_ROWP);
    int*   col    = (int*)(ws + OFF_COL);
    int*   bsum   = (int*)(ws + OFF_BSUM);
    float* out    = (float*)d_out;

    // degcnt and fillc are adjacent: zero both in one launch (ws is poisoned)
    k_zero<<<(2 * N_NODES + 255) / 256, 256, 0, stream>>>(degcnt, 2 * N_NODES);
    k_degree<<<(N_EDGES + 255) / 256, 256, 0, stream>>>(dst, degcnt);
    k_dis<<<(N_NODES + 255) / 256, 256, 0, stream>>>(degcnt, dis);
    k_scan1<<<98, 1024, 0, stream>>>(degcnt, rowptr, bsum);
    k_scan2<<<1, 64, 0, stream>>>(bsum, 98);
    k_scan3<<<98, 1024, 0, stream>>>(rowptr, bsum);
    k_fill<<<(N_EDGES + 255) / 256, 256, 0, stream>>>(src, dst, rowptr, fillc, col);

    // layer 1
    k_gemm<<<2048, 256, 0, stream>>>(x, W1, hw);
    k_agg<true><<<4096, 256, 0, stream>>>(hw, rowptr, col, dis, b1, h);
    // layer 2
    k_gemm<<<2048, 256, 0, stream>>>(h, W2, hw);
    k_agg<true><<<4096, 256, 0, stream>>>(hw, rowptr, col, dis, b2, h);
    // layer 3
    k_gemm<<<2048, 256, 0, stream>>>(h, W3, hw);
    k_agg<false><<<4096, 256, 0, stream>>>(hw, rowptr, col, dis, b3, h);

    // global max pool
    k_pool_init<<<(N_GRAPHS * F + 255) / 256, 256, 0, stream>>>(out);
    k_pool<<<512, 256, 0, stream>>>(h, batch, out);
}

// Round 2
// 323.363 us; speedup vs baseline: 1.4773x; 1.4773x over previous
//
#include <hip/hip_runtime.h>
#include <math.h>

#define N_NODES  100000
#define N_EDGES  800000
#define F        64
#define N_GRAPHS 64

// ---------------- workspace layout (bytes) ----------------
#define OFF_H    0u           // float[N_NODES*F]   25,600,000
#define OFF_HW   25600000u    // float[N_NODES*F]   25,600,000
#define OFF_DIS  51200000u    // float[N_NODES]        400,000
#define OFF_DEG  51600000u    // int[N_NODES]          400,000
#define OFF_FILL 52000000u    // int[N_NODES]          400,000
#define OFF_ROWP 52400000u    // int[N_NODES+1]        400,004
#define OFF_COL  52800256u    // int[N_EDGES]        3,200,000
#define OFF_BSUM 56000256u    // int[128]
// total ~56.0 MB

__global__ void k_zero(int* __restrict__ p, int n) {
    int i = blockIdx.x * blockDim.x + threadIdx.x;
    if (i < n) p[i] = 0;
}

__global__ void k_degree(const int* __restrict__ dst, int* __restrict__ degcnt) {
    int e = blockIdx.x * blockDim.x + threadIdx.x;
    if (e < N_EDGES) atomicAdd(&degcnt[dst[e]], 1);
}

__global__ void k_dis(const int* __restrict__ degcnt, float* __restrict__ dis) {
    int i = blockIdx.x * blockDim.x + threadIdx.x;
    if (i < N_NODES) dis[i] = rsqrtf((float)degcnt[i] + 1.0f);
}

// block-level inclusive scan of degcnt -> rowptr[i+1]; block totals -> bsum
__global__ void k_scan1(const int* __restrict__ degcnt, int* __restrict__ rowptr,
                        int* __restrict__ bsum) {
    __shared__ int s[1024];
    int i = blockIdx.x * 1024 + threadIdx.x;
    int v = (i < N_NODES) ? degcnt[i] : 0;
    s[threadIdx.x] = v;
    __syncthreads();
    for (int off = 1; off < 1024; off <<= 1) {
        int t = (threadIdx.x >= off) ? s[threadIdx.x - off] : 0;
        __syncthreads();
        s[threadIdx.x] += t;
        __syncthreads();
    }
    if (i < N_NODES) rowptr[i + 1] = s[threadIdx.x];
    if (threadIdx.x == 1023) bsum[blockIdx.x] = s[1023];
}

__global__ void k_scan2(int* __restrict__ bsum, int nb) {
    if (blockIdx.x == 0 && threadIdx.x == 0) {
        int acc = 0;
        for (int b = 0; b < nb; ++b) { int v = bsum[b]; bsum[b] = acc; acc += v; }
    }
}

__global__ void k_scan3(int* __restrict__ rowptr, const int* __restrict__ bsum) {
    int i = blockIdx.x * 1024 + threadIdx.x;
    if (i < N_NODES) rowptr[i + 1] += bsum[blockIdx.x];
    if (i == 0) rowptr[0] = 0;
}

__global__ void k_fill(const int* __restrict__ src, const int* __restrict__ dst,
                       const int* __restrict__ rowptr, int* __restrict__ fillc,
                       int* __restrict__ col) {
    int e = blockIdx.x * blockDim.x + threadIdx.x;
    if (e < N_EDGES) {
        int d = dst[e];
        int pos = rowptr[d] + atomicAdd(&fillc[d], 1);
        col[pos] = src[e];
    }
}

// hw[r][f] = sum_k hin[r][k] * W[k][f].
// wave <-> (64-row chunk rc, 16-feature quarter fq); lane = row.
// W rows come in via s_load (wave-uniform address); h row via float4 gathers.
// Per thread: 16 accumulators, 1024 FMAs (v_fmac_f32 v,s,v).
__global__ __launch_bounds__(256) void k_gemm(const float* __restrict__ hin,
                                              const float* __restrict__ W,
                                              float* __restrict__ hout) {
    int lane = threadIdx.x & 63;
    int wid  = (blockIdx.x * blockDim.x + threadIdx.x) >> 6;
    int fq = __builtin_amdgcn_readfirstlane(wid & 3);   // uniform -> W scalarizes
    int rc = __builtin_amdgcn_readfirstlane(wid >> 2);
    int row = rc * 64 + lane;
    bool valid = row < N_NODES;
    int rowc = valid ? row : (N_NODES - 1);
    const float* hrow = hin + (size_t)rowc * F;
    int fbase = fq * 16;

    float acc[16];
#pragma unroll
    for (int i = 0; i < 16; ++i) acc[i] = 0.f;

    for (int k0 = 0; k0 < 16; ++k0) {
        float4 hv = *(const float4*)(hrow + k0 * 4);
        float hks[4] = {hv.x, hv.y, hv.z, hv.w};
        const float* w0 = W + (k0 * 4) * F + fbase;     // uniform address
#pragma unroll
        for (int kk = 0; kk < 4; ++kk) {
            float hk = hks[kk];
            const float* wr = w0 + kk * F;
#pragma unroll
            for (int f = 0; f < 16; ++f)
                acc[f] = fmaf(hk, wr[f], acc[f]);
        }
    }
    if (valid) {
        float4* orow = (float4*)(hout + (size_t)row * F + fbase);
#pragma unroll
        for (int i = 0; i < 4; ++i)
            orow[i] = make_float4(acc[4*i], acc[4*i+1], acc[4*i+2], acc[4*i+3]);
    }
}

// h_out[n] = dis[n]*( sum_{e: dst=n} dis[src]*hw[src] + dis[n]*hw[n] ) + b,
// optional relu.  One wave per node, lane = feature.
// wid readfirstlane'd so rowptr/col/dis loads scalarize (s_load), leaving
// only the 256B hw-row gather on the vector pipe.
template<bool RELU>
__global__ __launch_bounds__(256) void k_agg(const float* __restrict__ hw,
                                             const int* __restrict__ rowptr,
                                             const int* __restrict__ col,
                                             const float* __restrict__ dis,
                                             const float* __restrict__ bias,
                                             float* __restrict__ hout) {
    int lane = threadIdx.x & 63;
    int wid  = __builtin_amdgcn_readfirstlane((blockIdx.x * blockDim.x + threadIdx.x) >> 6);
    int nwaves = (gridDim.x * blockDim.x) >> 6;
    float bv = bias[lane];
    for (int n = wid; n < N_NODES; n += nwaves) {
        int e0 = rowptr[n], e1 = rowptr[n + 1];
        float dn = dis[n];
        float acc = dn * hw[(size_t)n * F + lane];
        int e = e0;
        for (; e + 3 < e1; e += 4) {          // 4 gathers in flight
            int s0 = col[e], s1 = col[e + 1], s2 = col[e + 2], s3 = col[e + 3];
            float d0 = dis[s0], d1 = dis[s1], d2 = dis[s2], d3 = dis[s3];
            float v0 = hw[(size_t)s0 * F + lane];
            float v1 = hw[(size_t)s1 * F + lane];
            float v2 = hw[(size_t)s2 * F + lane];
            float v3 = hw[(size_t)s3 * F + lane];
            acc = fmaf(d0, v0, acc);
            acc = fmaf(d1, v1, acc);
            acc = fmaf(d2, v2, acc);
            acc = fmaf(d3, v3, acc);
        }
        for (; e < e1; ++e) {
            int s = col[e];
            acc = fmaf(dis[s], hw[(size_t)s * F + lane], acc);
        }
        float res = fmaf(dn, acc, bv);
        if (RELU) res = fmaxf(res, 0.f);
        hout[(size_t)n * F + lane] = res;
    }
}

__global__ void k_pool_init(float* __restrict__ out) {
    int i = blockIdx.x * blockDim.x + threadIdx.x;
    if (i < N_GRAPHS * F) out[i] = -INFINITY;
}

__device__ inline void atomicMaxFloat(float* addr, float v) {
    if (v >= 0.f) atomicMax((int*)addr, __float_as_int(v));
    else          atomicMin((unsigned int*)addr, __float_as_uint(v));
}

// batch is sorted: each wave scans a contiguous node chunk, keeps running max,
// flushes on graph boundary.
__global__ __launch_bounds__(256) void k_pool(const float* __restrict__ h,
                                              const int* __restrict__ batch,
                                              float* __restrict__ out) {
    int lane = threadIdx.x & 63;
    int wid  = __builtin_amdgcn_readfirstlane((blockIdx.x * blockDim.x + threadIdx.x) >> 6);
    int nwaves = (gridDim.x * blockDim.x) >> 6;
    int per = (N_NODES + nwaves - 1) / nwaves;
    int n0 = wid * per, n1 = min(N_NODES, n0 + per);
    if (n0 >= n1) return;
    float acc = -INFINITY;
    int cur = batch[n0];
    for (int n = n0; n < n1; ++n) {
        int g = batch[n];
        if (g != cur) {
            atomicMaxFloat(&out[cur * F + lane], acc);
            acc = -INFINITY; cur = g;
        }
        acc = fmaxf(acc, h[(size_t)n * F + lane]);
    }
    atomicMaxFloat(&out[cur * F + lane], acc);
}

extern "C" void kernel_launch(void* const* d_in, const int* in_sizes, int n_in,
                              void* d_out, int out_size, void* d_ws, size_t ws_size,
                              hipStream_t stream) {
    const float* x     = (const float*)d_in[0];
    const int*   ei    = (const int*)d_in[1];
    const int*   batch = (const int*)d_in[2];
    const float* W1 = (const float*)d_in[3];
    const float* b1 = (const float*)d_in[4];
    const float* W2 = (const float*)d_in[5];
    const float* b2 = (const float*)d_in[6];
    const float* W3 = (const float*)d_in[7];
    const float* b3 = (const float*)d_in[8];
    const int* src = ei;
    const int* dst = ei + N_EDGES;

    char* ws = (char*)d_ws;
    float* h      = (float*)(ws + OFF_H);
    float* hw     = (float*)(ws + OFF_HW);
    float* dis    = (float*)(ws + OFF_DIS);
    int*   degcnt = (int*)(ws + OFF_DEG);
    int*   fillc  = (int*)(ws + OFF_FILL);
    int*   rowptr = (int*)(ws + OFF_ROWP);
    int*   col    = (int*)(ws + OFF_COL);
    int*   bsum   = (int*)(ws + OFF_BSUM);
    float* out    = (float*)d_out;

    // degcnt and fillc are adjacent: zero both in one launch (ws is poisoned)
    k_zero<<<(2 * N_NODES + 255) / 256, 256, 0, stream>>>(degcnt, 2 * N_NODES);
    k_degree<<<(N_EDGES + 255) / 256, 256, 0, stream>>>(dst, degcnt);
    k_dis<<<(N_NODES + 255) / 256, 256, 0, stream>>>(degcnt, dis);
    k_scan1<<<98, 1024, 0, stream>>>(degcnt, rowptr, bsum);
    k_scan2<<<1, 64, 0, stream>>>(bsum, 98);
    k_scan3<<<98, 1024, 0, stream>>>(rowptr, bsum);
    k_fill<<<(N_EDGES + 255) / 256, 256, 0, stream>>>(src, dst, rowptr, fillc, col);

    const int GEMM_BLOCKS = ((N_NODES + 63) / 64);   // 1563: one wave-quad per 64-row chunk

    // layer 1
    k_gemm<<<GEMM_BLOCKS, 256, 0, stream>>>(x, W1, hw);
    k_agg<true><<<4096, 256, 0, stream>>>(hw, rowptr, col, dis, b1, h);
    // layer 2
    k_gemm<<<GEMM_BLOCKS, 256, 0, stream>>>(h, W2, hw);
    k_agg<true><<<4096, 256, 0, stream>>>(hw, rowptr, col, dis, b2, h);
    // layer 3
    k_gemm<<<GEMM_BLOCKS, 256, 0, stream>>>(h, W3, hw);
    k_agg<false><<<4096, 256, 0, stream>>>(hw, rowptr, col, dis, b3, h);

    // global max pool
    k_pool_init<<<(N_GRAPHS * F + 255) / 256, 256, 0, stream>>>(out);
    k_pool<<<512, 256, 0, stream>>>(h, batch, out);
}

// Round 3
// 278.544 us; speedup vs baseline: 1.7150x; 1.1609x over previous
//
#include <hip/hip_runtime.h>
#include <math.h>

#define N_NODES  100000
#define N_EDGES  800000
#define F        64
#define N_GRAPHS 64

// ---------------- workspace layout (bytes) ----------------
#define OFF_H    0u           // float[N_NODES*F]   25,600,000  (also rank[] during CSR build)
#define OFF_HW   25600000u    // float[N_NODES*F]   25,600,000  (holds hws = dis*h*W)
#define OFF_DIS  51200000u    // float[N_NODES]        400,000
#define OFF_DEG  51600000u    // int[N_NODES]          400,000
#define OFF_FILL 52000000u    // (unused)
#define OFF_ROWP 52400000u    // int[N_NODES+1]        400,004
#define OFF_COL  52800256u    // int[N_EDGES]        3,200,000
#define OFF_BSUM 56000256u    // int[128]
// total ~56.0 MB

__global__ void k_zero(int* __restrict__ p, int n) {
    int i = blockIdx.x * blockDim.x + threadIdx.x;
    if (i < n) p[i] = 0;
}

// degree count AND per-edge rank (return value of the atomic we already pay)
__global__ void k_degree(const int* __restrict__ dst, int* __restrict__ degcnt,
                         int* __restrict__ rank) {
    int e = blockIdx.x * blockDim.x + threadIdx.x;
    if (e < N_EDGES) rank[e] = atomicAdd(&degcnt[dst[e]], 1);
}

__global__ void k_dis(const int* __restrict__ degcnt, float* __restrict__ dis) {
    int i = blockIdx.x * blockDim.x + threadIdx.x;
    if (i < N_NODES) dis[i] = rsqrtf((float)degcnt[i] + 1.0f);
}

// block-level inclusive scan of degcnt -> rowptr[i+1]; block totals -> bsum
__global__ void k_scan1(const int* __restrict__ degcnt, int* __restrict__ rowptr,
                        int* __restrict__ bsum) {
    __shared__ int s[1024];
    int i = blockIdx.x * 1024 + threadIdx.x;
    int v = (i < N_NODES) ? degcnt[i] : 0;
    s[threadIdx.x] = v;
    __syncthreads();
    for (int off = 1; off < 1024; off <<= 1) {
        int t = (threadIdx.x >= off) ? s[threadIdx.x - off] : 0;
        __syncthreads();
        s[threadIdx.x] += t;
        __syncthreads();
    }
    if (i < N_NODES) rowptr[i + 1] = s[threadIdx.x];
    if (threadIdx.x == 1023) bsum[blockIdx.x] = s[1023];
}

__global__ void k_scan2(int* __restrict__ bsum, int nb) {
    if (blockIdx.x == 0 && threadIdx.x == 0) {
        int acc = 0;
        for (int b = 0; b < nb; ++b) { int v = bsum[b]; bsum[b] = acc; acc += v; }
    }
}

__global__ void k_scan3(int* __restrict__ rowptr, const int* __restrict__ bsum) {
    int i = blockIdx.x * 1024 + threadIdx.x;
    if (i < N_NODES) rowptr[i + 1] += bsum[blockIdx.x];
    if (i == 0) rowptr[0] = 0;
}

// no atomics: position comes from rowptr + precomputed rank
__global__ void k_fill(const int* __restrict__ src, const int* __restrict__ dst,
                       const int* __restrict__ rowptr, const int* __restrict__ rank,
                       int* __restrict__ col) {
    int e = blockIdx.x * blockDim.x + threadIdx.x;
    if (e < N_EDGES) {
        int d = dst[e];
        col[rowptr[d] + rank[e]] = src[e];
    }
}

// hws[r][f] = dis[r] * sum_k hin[r][k] * W[k][f].
// wave <-> (64-row chunk rc, 16-feature quarter fq); lane = row.
// W rows via s_load (wave-uniform address); h row via float4 gathers
// (the 4 fq-waves of a chunk share a block -> L1 reuse of the 16KB tile).
__global__ __launch_bounds__(256) void k_gemm(const float* __restrict__ hin,
                                              const float* __restrict__ W,
                                              const float* __restrict__ dis,
                                              float* __restrict__ hout) {
    int lane = threadIdx.x & 63;
    int wid  = (blockIdx.x * blockDim.x + threadIdx.x) >> 6;
    int fq = __builtin_amdgcn_readfirstlane(wid & 3);   // uniform -> W scalarizes
    int rc = __builtin_amdgcn_readfirstlane(wid >> 2);
    int row = rc * 64 + lane;
    bool valid = row < N_NODES;
    int rowc = valid ? row : (N_NODES - 1);
    const float* hrow = hin + (size_t)rowc * F;
    int fbase = fq * 16;

    float acc[16];
#pragma unroll
    for (int i = 0; i < 16; ++i) acc[i] = 0.f;

    for (int k0 = 0; k0 < 16; ++k0) {
        float4 hv = *(const float4*)(hrow + k0 * 4);
        float hks[4] = {hv.x, hv.y, hv.z, hv.w};
        const float* w0 = W + (k0 * 4) * F + fbase;     // uniform address
#pragma unroll
        for (int kk = 0; kk < 4; ++kk) {
            float hk = hks[kk];
            const float* wr = w0 + kk * F;
#pragma unroll
            for (int f = 0; f < 16; ++f)
                acc[f] = fmaf(hk, wr[f], acc[f]);
        }
    }
    if (valid) {
        float ds = dis[row];
        float4* orow = (float4*)(hout + (size_t)row * F + fbase);
#pragma unroll
        for (int i = 0; i < 4; ++i)
            orow[i] = make_float4(ds * acc[4*i], ds * acc[4*i+1],
                                  ds * acc[4*i+2], ds * acc[4*i+3]);
    }
}

// h_out[n] = dis[n]*( hws[n] + sum_{e: dst=n} hws[src] ) + b   (hws pre-scaled by dis)
// optional relu.  One wave per node, lane = feature. Pure adds per edge,
// col via s_load, 8 gathers in flight.
template<bool RELU>
__global__ __launch_bounds__(256) void k_agg(const float* __restrict__ hws,
                                             const int* __restrict__ rowptr,
                                             const int* __restrict__ col,
                                             const float* __restrict__ dis,
                                             const float* __restrict__ bias,
                                             float* __restrict__ hout) {
    int lane = threadIdx.x & 63;
    int wid  = __builtin_amdgcn_readfirstlane((blockIdx.x * blockDim.x + threadIdx.x) >> 6);
    int nwaves = (gridDim.x * blockDim.x) >> 6;
    float bv = bias[lane];
    for (int n = wid; n < N_NODES; n += nwaves) {
        int e0 = rowptr[n], e1 = rowptr[n + 1];
        float dn = dis[n];
        float acc = hws[(size_t)n * F + lane];
        int e = e0;
        for (; e + 7 < e1; e += 8) {          // 8 gathers in flight
            float v0 = hws[(size_t)col[e]     * F + lane];
            float v1 = hws[(size_t)col[e + 1] * F + lane];
            float v2 = hws[(size_t)col[e + 2] * F + lane];
            float v3 = hws[(size_t)col[e + 3] * F + lane];
            float v4 = hws[(size_t)col[e + 4] * F + lane];
            float v5 = hws[(size_t)col[e + 5] * F + lane];
            float v6 = hws[(size_t)col[e + 6] * F + lane];
            float v7 = hws[(size_t)col[e + 7] * F + lane];
            acc += v0 + v1 + v2 + v3 + v4 + v5 + v6 + v7;
        }
        if (e + 3 < e1) {
            float v0 = hws[(size_t)col[e]     * F + lane];
            float v1 = hws[(size_t)col[e + 1] * F + lane];
            float v2 = hws[(size_t)col[e + 2] * F + lane];
            float v3 = hws[(size_t)col[e + 3] * F + lane];
            acc += v0 + v1 + v2 + v3;
            e += 4;
        }
        for (; e < e1; ++e)
            acc += hws[(size_t)col[e] * F + lane];
        float res = fmaf(dn, acc, bv);
        if (RELU) res = fmaxf(res, 0.f);
        hout[(size_t)n * F + lane] = res;
    }
}

__global__ void k_pool_init(float* __restrict__ out) {
    int i = blockIdx.x * blockDim.x + threadIdx.x;
    if (i < N_GRAPHS * F) out[i] = -INFINITY;
}

__device__ inline void atomicMaxFloat(float* addr, float v) {
    if (v >= 0.f) atomicMax((int*)addr, __float_as_int(v));
    else          atomicMin((unsigned int*)addr, __float_as_uint(v));
}

// batch is sorted: each wave scans a contiguous node chunk, keeps running max,
// flushes on graph boundary.
__global__ __launch_bounds__(256) void k_pool(const float* __restrict__ h,
                                              const int* __restrict__ batch,
                                              float* __restrict__ out) {
    int lane = threadIdx.x & 63;
    int wid  = __builtin_amdgcn_readfirstlane((blockIdx.x * blockDim.x + threadIdx.x) >> 6);
    int nwaves = (gridDim.x * blockDim.x) >> 6;
    int per = (N_NODES + nwaves - 1) / nwaves;
    int n0 = wid * per, n1 = min(N_NODES, n0 + per);
    if (n0 >= n1) return;
    float acc = -INFINITY;
    int cur = batch[n0];
    for (int n = n0; n < n1; ++n) {
        int g = batch[n];
        if (g != cur) {
            atomicMaxFloat(&out[cur * F + lane], acc);
            acc = -INFINITY; cur = g;
        }
        acc = fmaxf(acc, h[(size_t)n * F + lane]);
    }
    atomicMaxFloat(&out[cur * F + lane], acc);
}

extern "C" void kernel_launch(void* const* d_in, const int* in_sizes, int n_in,
                              void* d_out, int out_size, void* d_ws, size_t ws_size,
                              hipStream_t stream) {
    const float* x     = (const float*)d_in[0];
    const int*   ei    = (const int*)d_in[1];
    const int*   batch = (const int*)d_in[2];
    const float* W1 = (const float*)d_in[3];
    const float* b1 = (const float*)d_in[4];
    const float* W2 = (const float*)d_in[5];
    const float* b2 = (const float*)d_in[6];
    const float* W3 = (const float*)d_in[7];
    const float* b3 = (const float*)d_in[8];
    const int* src = ei;
    const int* dst = ei + N_EDGES;

    char* ws = (char*)d_ws;
    float* h      = (float*)(ws + OFF_H);
    int*   rank   = (int*)(ws + OFF_H);      // alias: only live during CSR build
    float* hw     = (float*)(ws + OFF_HW);
    float* dis    = (float*)(ws + OFF_DIS);
    int*   degcnt = (int*)(ws + OFF_DEG);
    int*   rowptr = (int*)(ws + OFF_ROWP);
    int*   col    = (int*)(ws + OFF_COL);
    int*   bsum   = (int*)(ws + OFF_BSUM);
    float* out    = (float*)d_out;

    k_zero<<<(N_NODES + 255) / 256, 256, 0, stream>>>(degcnt, N_NODES);
    k_degree<<<(N_EDGES + 255) / 256, 256, 0, stream>>>(dst, degcnt, rank);
    k_dis<<<(N_NODES + 255) / 256, 256, 0, stream>>>(degcnt, dis);
    k_scan1<<<98, 1024, 0, stream>>>(degcnt, rowptr, bsum);
    k_scan2<<<1, 64, 0, stream>>>(bsum, 98);
    k_scan3<<<98, 1024, 0, stream>>>(rowptr, bsum);
    k_fill<<<(N_EDGES + 255) / 256, 256, 0, stream>>>(src, dst, rowptr, rank, col);

    const int GEMM_BLOCKS = ((N_NODES + 63) / 64);   // one 4-wave block per 64-row chunk

    // layer 1
    k_gemm<<<GEMM_BLOCKS, 256, 0, stream>>>(x, W1, dis, hw);
    k_agg<true><<<4096, 256, 0, stream>>>(hw, rowptr, col, dis, b1, h);
    // layer 2
    k_gemm<<<GEMM_BLOCKS, 256, 0, stream>>>(h, W2, dis, hw);
    k_agg<true><<<4096, 256, 0, stream>>>(hw, rowptr, col, dis, b2, h);
    // layer 3
    k_gemm<<<GEMM_BLOCKS, 256, 0, stream>>>(h, W3, dis, hw);
    k_agg<false><<<4096, 256, 0, stream>>>(hw, rowptr, col, dis, b3, h);

    // global max pool
    k_pool_init<<<(N_GRAPHS * F + 255) / 256, 256, 0, stream>>>(out);
    k_pool<<<512, 256, 0, stream>>>(h, batch, out);
}

// Round 4
// 240.030 us; speedup vs baseline: 1.9901x; 1.1605x over previous
//
#include <hip/hip_runtime.h>
#include <math.h>

#define N_NODES  100000
#define N_EDGES  800000
#define F        64
#define N_GRAPHS 64

// ---------------- workspace layout (bytes) ----------------
#define OFF_H    0u           // float[N_NODES*F]   25,600,000  (also rank[] during CSR build)
#define OFF_HW   25600000u    // ushort[N_NODES*F]  12,800,000  (hws = dis*h*W, bf16)
#define OFF_DIS  51200000u    // float[N_NODES]        400,000
#define OFF_DEG  51600000u    // int[N_NODES]          400,000
#define OFF_ROWP 52400000u    // int[N_NODES+1]        400,004
#define OFF_COL  52800256u    // int[N_EDGES]        3,200,000
#define OFF_BSUM 56000256u    // int[128]
// total ~56.0 MB

__device__ inline ushort f2bf(float f) {               // round-to-nearest-even
    uint u = __float_as_uint(f);
    u = (u + 0x7FFFu + ((u >> 16) & 1u)) >> 16;
    return (ushort)u;
}
__device__ inline float bf2f(ushort s) {
    return __uint_as_float(((uint)s) << 16);
}

__global__ void k_zero(int* __restrict__ p, int n) {
    int i = blockIdx.x * blockDim.x + threadIdx.x;
    if (i < n) p[i] = 0;
}

// degree count AND per-edge rank (return value of the atomic we already pay)
__global__ void k_degree(const int* __restrict__ dst, int* __restrict__ degcnt,
                         int* __restrict__ rank) {
    int e = blockIdx.x * blockDim.x + threadIdx.x;
    if (e < N_EDGES) rank[e] = atomicAdd(&degcnt[dst[e]], 1);
}

// block-level inclusive scan of degcnt -> rowptr[i+1]; block totals -> bsum.
// Also emits dis = rsqrt(deg+1) (fused former k_dis pass).
__global__ void k_scan1(const int* __restrict__ degcnt, int* __restrict__ rowptr,
                        int* __restrict__ bsum, float* __restrict__ dis) {
    __shared__ int s[1024];
    int i = blockIdx.x * 1024 + threadIdx.x;
    int v = (i < N_NODES) ? degcnt[i] : 0;
    if (i < N_NODES) dis[i] = rsqrtf((float)v + 1.0f);
    s[threadIdx.x] = v;
    __syncthreads();
    for (int off = 1; off < 1024; off <<= 1) {
        int t = (threadIdx.x >= off) ? s[threadIdx.x - off] : 0;
        __syncthreads();
        s[threadIdx.x] += t;
        __syncthreads();
    }
    if (i < N_NODES) rowptr[i + 1] = s[threadIdx.x];
    if (threadIdx.x == 1023) bsum[blockIdx.x] = s[1023];
}

__global__ void k_scan2(int* __restrict__ bsum, int nb) {
    if (blockIdx.x == 0 && threadIdx.x == 0) {
        int acc = 0;
        for (int b = 0; b < nb; ++b) { int v = bsum[b]; bsum[b] = acc; acc += v; }
    }
}

__global__ void k_scan3(int* __restrict__ rowptr, const int* __restrict__ bsum) {
    int i = blockIdx.x * 1024 + threadIdx.x;
    if (i < N_NODES) rowptr[i + 1] += bsum[blockIdx.x];
    if (i == 0) rowptr[0] = 0;
}

// no atomics: position comes from rowptr + precomputed rank
__global__ void k_fill(const int* __restrict__ src, const int* __restrict__ dst,
                       const int* __restrict__ rowptr, const int* __restrict__ rank,
                       int* __restrict__ col) {
    int e = blockIdx.x * blockDim.x + threadIdx.x;
    if (e < N_EDGES) {
        int d = dst[e];
        col[rowptr[d] + rank[e]] = src[e];
    }
}

// hws[r][f] = bf16( dis[r] * sum_k hin[r][k] * W[k][f] ).
// wave <-> (64-row chunk rc, 16-feature quarter fq); lane = row.
// W rows via s_load (wave-uniform address); h row via float4 gathers.
__global__ __launch_bounds__(256) void k_gemm(const float* __restrict__ hin,
                                              const float* __restrict__ W,
                                              const float* __restrict__ dis,
                                              ushort* __restrict__ hout) {
    int lane = threadIdx.x & 63;
    int wid  = (blockIdx.x * blockDim.x + threadIdx.x) >> 6;
    int fq = __builtin_amdgcn_readfirstlane(wid & 3);   // uniform -> W scalarizes
    int rc = __builtin_amdgcn_readfirstlane(wid >> 2);
    int row = rc * 64 + lane;
    bool valid = row < N_NODES;
    int rowc = valid ? row : (N_NODES - 1);
    const float* hrow = hin + (size_t)rowc * F;
    int fbase = fq * 16;

    float acc[16];
#pragma unroll
    for (int i = 0; i < 16; ++i) acc[i] = 0.f;

    for (int k0 = 0; k0 < 16; ++k0) {
        float4 hv = *(const float4*)(hrow + k0 * 4);
        float hks[4] = {hv.x, hv.y, hv.z, hv.w};
        const float* w0 = W + (k0 * 4) * F + fbase;     // uniform address
#pragma unroll
        for (int kk = 0; kk < 4; ++kk) {
            float hk = hks[kk];
            const float* wr = w0 + kk * F;
#pragma unroll
            for (int f = 0; f < 16; ++f)
                acc[f] = fmaf(hk, wr[f], acc[f]);
        }
    }
    if (valid) {
        float ds = dis[row];
        uint p[8];
#pragma unroll
        for (int i = 0; i < 8; ++i)
            p[i] = (uint)f2bf(ds * acc[2*i]) | ((uint)f2bf(ds * acc[2*i+1]) << 16);
        uint4* orow = (uint4*)(hout + (size_t)row * F + fbase);
        orow[0] = make_uint4(p[0], p[1], p[2], p[3]);
        orow[1] = make_uint4(p[4], p[5], p[6], p[7]);
    }
}

// h_out[n] = dis[n]*( hws[n] + sum_{e: dst=n} hws[src] ) + b   (hws pre-scaled by dis,
// stored bf16 -> 128B gather rows). f32 accumulate, optional relu, f32 output.
// One wave per node, lane = feature; col via s_load, 8 gathers in flight.
template<bool RELU>
__global__ __launch_bounds__(256) void k_agg(const ushort* __restrict__ hws,
                                             const int* __restrict__ rowptr,
                                             const int* __restrict__ col,
                                             const float* __restrict__ dis,
                                             const float* __restrict__ bias,
                                             float* __restrict__ hout) {
    int lane = threadIdx.x & 63;
    int wid  = __builtin_amdgcn_readfirstlane((blockIdx.x * blockDim.x + threadIdx.x) >> 6);
    int nwaves = (gridDim.x * blockDim.x) >> 6;
    float bv = bias[lane];
    for (int n = wid; n < N_NODES; n += nwaves) {
        int e0 = rowptr[n], e1 = rowptr[n + 1];
        float dn = dis[n];
        float acc = bf2f(hws[(size_t)n * F + lane]);
        int e = e0;
        for (; e + 7 < e1; e += 8) {          // 8 gathers in flight
            ushort v0 = hws[(size_t)col[e]     * F + lane];
            ushort v1 = hws[(size_t)col[e + 1] * F + lane];
            ushort v2 = hws[(size_t)col[e + 2] * F + lane];
            ushort v3 = hws[(size_t)col[e + 3] * F + lane];
            ushort v4 = hws[(size_t)col[e + 4] * F + lane];
            ushort v5 = hws[(size_t)col[e + 5] * F + lane];
            ushort v6 = hws[(size_t)col[e + 6] * F + lane];
            ushort v7 = hws[(size_t)col[e + 7] * F + lane];
            acc += bf2f(v0) + bf2f(v1) + bf2f(v2) + bf2f(v3)
                 + bf2f(v4) + bf2f(v5) + bf2f(v6) + bf2f(v7);
        }
        if (e + 3 < e1) {
            ushort v0 = hws[(size_t)col[e]     * F + lane];
            ushort v1 = hws[(size_t)col[e + 1] * F + lane];
            ushort v2 = hws[(size_t)col[e + 2] * F + lane];
            ushort v3 = hws[(size_t)col[e + 3] * F + lane];
            acc += bf2f(v0) + bf2f(v1) + bf2f(v2) + bf2f(v3);
            e += 4;
        }
        for (; e < e1; ++e)
            acc += bf2f(hws[(size_t)col[e] * F + lane]);
        float res = fmaf(dn, acc, bv);
        if (RELU) res = fmaxf(res, 0.f);
        hout[(size_t)n * F + lane] = res;
    }
}

__global__ void k_pool_init(float* __restrict__ out) {
    int i = blockIdx.x * blockDim.x + threadIdx.x;
    if (i < N_GRAPHS * F) out[i] = -INFINITY;
}

__device__ inline void atomicMaxFloat(float* addr, float v) {
    if (v >= 0.f) atomicMax((int*)addr, __float_as_int(v));
    else          atomicMin((unsigned int*)addr, __float_as_uint(v));
}

// batch is sorted: each wave scans a contiguous node chunk, keeps running max,
// flushes on graph boundary.
__global__ __launch_bounds__(256) void k_pool(const float* __restrict__ h,
                                              const int* __restrict__ batch,
                                              float* __restrict__ out) {
    int lane = threadIdx.x & 63;
    int wid  = __builtin_amdgcn_readfirstlane((blockIdx.x * blockDim.x + threadIdx.x) >> 6);
    int nwaves = (gridDim.x * blockDim.x) >> 6;
    int per = (N_NODES + nwaves - 1) / nwaves;
    int n0 = wid * per, n1 = min(N_NODES, n0 + per);
    if (n0 >= n1) return;
    float acc = -INFINITY;
    int cur = batch[n0];
    for (int n = n0; n < n1; ++n) {
        int g = batch[n];
        if (g != cur) {
            atomicMaxFloat(&out[cur * F + lane], acc);
            acc = -INFINITY; cur = g;
        }
        acc = fmaxf(acc, h[(size_t)n * F + lane]);
    }
    atomicMaxFloat(&out[cur * F + lane], acc);
}

extern "C" void kernel_launch(void* const* d_in, const int* in_sizes, int n_in,
                              void* d_out, int out_size, void* d_ws, size_t ws_size,
                              hipStream_t stream) {
    const float* x     = (const float*)d_in[0];
    const int*   ei    = (const int*)d_in[1];
    const int*   batch = (const int*)d_in[2];
    const float* W1 = (const float*)d_in[3];
    const float* b1 = (const float*)d_in[4];
    const float* W2 = (const float*)d_in[5];
    const float* b2 = (const float*)d_in[6];
    const float* W3 = (const float*)d_in[7];
    const float* b3 = (const float*)d_in[8];
    const int* src = ei;
    const int* dst = ei + N_EDGES;

    char* ws = (char*)d_ws;
    float*  h      = (float*)(ws + OFF_H);
    int*    rank   = (int*)(ws + OFF_H);     // alias: only live during CSR build
    ushort* hw     = (ushort*)(ws + OFF_HW);
    float*  dis    = (float*)(ws + OFF_DIS);
    int*    degcnt = (int*)(ws + OFF_DEG);
    int*    rowptr = (int*)(ws + OFF_ROWP);
    int*    col    = (int*)(ws + OFF_COL);
    int*    bsum   = (int*)(ws + OFF_BSUM);
    float*  out    = (float*)d_out;

    k_zero<<<(N_NODES + 255) / 256, 256, 0, stream>>>(degcnt, N_NODES);
    k_degree<<<(N_EDGES + 255) / 256, 256, 0, stream>>>(dst, degcnt, rank);
    k_scan1<<<98, 1024, 0, stream>>>(degcnt, rowptr, bsum, dis);
    k_scan2<<<1, 64, 0, stream>>>(bsum, 98);
    k_scan3<<<98, 1024, 0, stream>>>(rowptr, bsum);
    k_fill<<<(N_EDGES + 255) / 256, 256, 0, stream>>>(src, dst, rowptr, rank, col);

    const int GEMM_BLOCKS = ((N_NODES + 63) / 64);   // one 4-wave block per 64-row chunk

    // layer 1
    k_gemm<<<GEMM_BLOCKS, 256, 0, stream>>>(x, W1, dis, hw);
    k_agg<true><<<4096, 256, 0, stream>>>(hw, rowptr, col, dis, b1, h);
    // layer 2
    k_gemm<<<GEMM_BLOCKS, 256, 0, stream>>>(h, W2, dis, hw);
    k_agg<true><<<4096, 256, 0, stream>>>(hw, rowptr, col, dis, b2, h);
    // layer 3
    k_gemm<<<GEMM_BLOCKS, 256, 0, stream>>>(h, W3, dis, hw);
    k_agg<false><<<4096, 256, 0, stream>>>(hw, rowptr, col, dis, b3, h);

    // global max pool
    k_pool_init<<<(N_GRAPHS * F + 255) / 256, 256, 0, stream>>>(out);
    k_pool<<<512, 256, 0, stream>>>(h, batch, out);
}

// Round 5
// 237.207 us; speedup vs baseline: 2.0138x; 1.0119x over previous
//
#include <hip/hip_runtime.h>
#include <math.h>

#define N_NODES  100000
#define N_EDGES  800000
#define F        64
#define N_GRAPHS 64

// ---------------- workspace layout (bytes) ----------------
#define OFF_H    0u           // ushort[N_NODES*F]  12,800,000 (bf16 h; also rank[] during CSR build)
#define OFF_HW   25600000u    // ushort[N_NODES*F]  12,800,000 (hws = dis*h*W, bf16)
#define OFF_DIS  51200000u    // float[N_NODES]        400,000
#define OFF_DEG  51600000u    // int[N_NODES]          400,000
#define OFF_ROWP 52400000u    // int[N_NODES+1]        400,004
#define OFF_COL  52800256u    // int[N_EDGES]        3,200,000
#define OFF_BSUM 56000256u    // int[128]
// total ~56.0 MB

__device__ inline ushort f2bf(float f) {               // round-to-nearest-even
    uint u = __float_as_uint(f);
    u = (u + 0x7FFFu + ((u >> 16) & 1u)) >> 16;
    return (ushort)u;
}
__device__ inline float bf2f(ushort s) {
    return __uint_as_float(((uint)s) << 16);
}

__global__ void k_zero(int* __restrict__ p, int n) {
    int i = blockIdx.x * blockDim.x + threadIdx.x;
    if (i < n) p[i] = 0;
}

// degree count AND per-edge rank (return value of the atomic we already pay)
__global__ void k_degree(const int* __restrict__ dst, int* __restrict__ degcnt,
                         int* __restrict__ rank) {
    int e = blockIdx.x * blockDim.x + threadIdx.x;
    if (e < N_EDGES) rank[e] = atomicAdd(&degcnt[dst[e]], 1);
}

// block-level inclusive scan of degcnt -> rowptr[i+1]; block totals -> bsum.
// Also emits dis = rsqrt(deg+1) (fused former k_dis pass).
__global__ void k_scan1(const int* __restrict__ degcnt, int* __restrict__ rowptr,
                        int* __restrict__ bsum, float* __restrict__ dis) {
    __shared__ int s[1024];
    int i = blockIdx.x * 1024 + threadIdx.x;
    int v = (i < N_NODES) ? degcnt[i] : 0;
    if (i < N_NODES) dis[i] = rsqrtf((float)v + 1.0f);
    s[threadIdx.x] = v;
    __syncthreads();
    for (int off = 1; off < 1024; off <<= 1) {
        int t = (threadIdx.x >= off) ? s[threadIdx.x - off] : 0;
        __syncthreads();
        s[threadIdx.x] += t;
        __syncthreads();
    }
    if (i < N_NODES) rowptr[i + 1] = s[threadIdx.x];
    if (threadIdx.x == 1023) bsum[blockIdx.x] = s[1023];
}

__global__ void k_scan2(int* __restrict__ bsum, int nb) {
    if (blockIdx.x == 0 && threadIdx.x == 0) {
        int acc = 0;
        for (int b = 0; b < nb; ++b) { int v = bsum[b]; bsum[b] = acc; acc += v; }
    }
}

__global__ void k_scan3(int* __restrict__ rowptr, const int* __restrict__ bsum) {
    int i = blockIdx.x * 1024 + threadIdx.x;
    if (i < N_NODES) rowptr[i + 1] += bsum[blockIdx.x];
    if (i == 0) rowptr[0] = 0;
}

// no atomics: position comes from rowptr + precomputed rank
__global__ void k_fill(const int* __restrict__ src, const int* __restrict__ dst,
                       const int* __restrict__ rowptr, const int* __restrict__ rank,
                       int* __restrict__ col) {
    int e = blockIdx.x * blockDim.x + threadIdx.x;
    if (e < N_EDGES) {
        int d = dst[e];
        col[rowptr[d] + rank[e]] = src[e];
    }
}

// hws[r][f] = bf16( dis[r] * sum_k hin[r][k] * W[k][f] ).
// wave <-> (64-row chunk rc, 16-feature quarter fq); lane = row.
// W rows via s_load (wave-uniform address); h row via 16B vector gathers.
// Templated on input type: float (layer 1 reads x) or ushort/bf16 (layers 2,3).
template<typename T>
__global__ __launch_bounds__(256) void k_gemm(const T* __restrict__ hin,
                                              const float* __restrict__ W,
                                              const float* __restrict__ dis,
                                              ushort* __restrict__ hout) {
    int lane = threadIdx.x & 63;
    int wid  = (blockIdx.x * blockDim.x + threadIdx.x) >> 6;
    int fq = __builtin_amdgcn_readfirstlane(wid & 3);   // uniform -> W scalarizes
    int rc = __builtin_amdgcn_readfirstlane(wid >> 2);
    int row = rc * 64 + lane;
    bool valid = row < N_NODES;
    int rowc = valid ? row : (N_NODES - 1);
    const T* hrow = hin + (size_t)rowc * F;
    int fbase = fq * 16;

    float acc[16];
#pragma unroll
    for (int i = 0; i < 16; ++i) acc[i] = 0.f;

    for (int k0 = 0; k0 < 8; ++k0) {                    // 8 k-octets
        float hks[8];
        if constexpr (sizeof(T) == 4) {                 // f32 input
            float4 a = *(const float4*)((const float*)hrow + k0 * 8);
            float4 b = *(const float4*)((const float*)hrow + k0 * 8 + 4);
            hks[0]=a.x; hks[1]=a.y; hks[2]=a.z; hks[3]=a.w;
            hks[4]=b.x; hks[5]=b.y; hks[6]=b.z; hks[7]=b.w;
        } else {                                        // bf16 input
            uint4 a = *(const uint4*)((const ushort*)hrow + k0 * 8);
            hks[0]=bf2f((ushort)(a.x & 0xFFFF)); hks[1]=bf2f((ushort)(a.x >> 16));
            hks[2]=bf2f((ushort)(a.y & 0xFFFF)); hks[3]=bf2f((ushort)(a.y >> 16));
            hks[4]=bf2f((ushort)(a.z & 0xFFFF)); hks[5]=bf2f((ushort)(a.z >> 16));
            hks[6]=bf2f((ushort)(a.w & 0xFFFF)); hks[7]=bf2f((ushort)(a.w >> 16));
        }
        const float* w0 = W + (k0 * 8) * F + fbase;     // uniform address
#pragma unroll
        for (int kk = 0; kk < 8; ++kk) {
            float hk = hks[kk];
            const float* wr = w0 + kk * F;
#pragma unroll
            for (int f = 0; f < 16; ++f)
                acc[f] = fmaf(hk, wr[f], acc[f]);
        }
    }
    if (valid) {
        float ds = dis[row];
        uint p[8];
#pragma unroll
        for (int i = 0; i < 8; ++i)
            p[i] = (uint)f2bf(ds * acc[2*i]) | ((uint)f2bf(ds * acc[2*i+1]) << 16);
        uint4* orow = (uint4*)(hout + (size_t)row * F + fbase);
        orow[0] = make_uint4(p[0], p[1], p[2], p[3]);
        orow[1] = make_uint4(p[4], p[5], p[6], p[7]);
    }
}

// h_out[n] = bf16( dis[n]*( hws[n] + sum_{e: dst=n} hws[src] ) + b ), optional relu.
// hws pre-scaled by dis (128B bf16 rows). One wave per TWO adjacent nodes
// (their CSR edge ranges are contiguous): joint 4+4 gather loop doubles
// memory-level parallelism across the rowptr->col->gather latency chain.
template<bool RELU>
__global__ __launch_bounds__(256) void k_agg(const ushort* __restrict__ hws,
                                             const int* __restrict__ rowptr,
                                             const int* __restrict__ col,
                                             const float* __restrict__ dis,
                                             const float* __restrict__ bias,
                                             ushort* __restrict__ hout) {
    int lane = threadIdx.x & 63;
    int wid  = __builtin_amdgcn_readfirstlane((blockIdx.x * blockDim.x + threadIdx.x) >> 6);
    int nwaves = (gridDim.x * blockDim.x) >> 6;
    float bv = bias[lane];
    for (int n = wid * 2; n < N_NODES; n += 2 * nwaves) {
        bool hasb = (n + 1) < N_NODES;
        int e0 = rowptr[n];
        int e1 = rowptr[n + 1];
        int e2 = hasb ? rowptr[n + 2] : e1;
        float acca = bf2f(hws[(size_t)n * F + lane]);
        float accb = hasb ? bf2f(hws[(size_t)(n + 1) * F + lane]) : 0.f;
        int ea = e0, eb = e1;
        // joint phase: 8 independent gathers in flight (4 per node)
        while (ea + 3 < e1 && eb + 3 < e2) {
            int sa0 = col[ea], sa1 = col[ea+1], sa2 = col[ea+2], sa3 = col[ea+3];
            int sb0 = col[eb], sb1 = col[eb+1], sb2 = col[eb+2], sb3 = col[eb+3];
            float va0 = bf2f(hws[(size_t)sa0 * F + lane]);
            float va1 = bf2f(hws[(size_t)sa1 * F + lane]);
            float va2 = bf2f(hws[(size_t)sa2 * F + lane]);
            float va3 = bf2f(hws[(size_t)sa3 * F + lane]);
            float vb0 = bf2f(hws[(size_t)sb0 * F + lane]);
            float vb1 = bf2f(hws[(size_t)sb1 * F + lane]);
            float vb2 = bf2f(hws[(size_t)sb2 * F + lane]);
            float vb3 = bf2f(hws[(size_t)sb3 * F + lane]);
            acca += va0 + va1 + va2 + va3;
            accb += vb0 + vb1 + vb2 + vb3;
            ea += 4; eb += 4;
        }
        // drain a
        for (; ea + 3 < e1; ea += 4) {
            float v0 = bf2f(hws[(size_t)col[ea]   * F + lane]);
            float v1 = bf2f(hws[(size_t)col[ea+1] * F + lane]);
            float v2 = bf2f(hws[(size_t)col[ea+2] * F + lane]);
            float v3 = bf2f(hws[(size_t)col[ea+3] * F + lane]);
            acca += v0 + v1 + v2 + v3;
        }
        for (; ea < e1; ++ea) acca += bf2f(hws[(size_t)col[ea] * F + lane]);
        // drain b
        for (; eb + 3 < e2; eb += 4) {
            float v0 = bf2f(hws[(size_t)col[eb]   * F + lane]);
            float v1 = bf2f(hws[(size_t)col[eb+1] * F + lane]);
            float v2 = bf2f(hws[(size_t)col[eb+2] * F + lane]);
            float v3 = bf2f(hws[(size_t)col[eb+3] * F + lane]);
            accb += v0 + v1 + v2 + v3;
        }
        for (; eb < e2; ++eb) accb += bf2f(hws[(size_t)col[eb] * F + lane]);

        float resa = fmaf(dis[n], acca, bv);
        if (RELU) resa = fmaxf(resa, 0.f);
        hout[(size_t)n * F + lane] = f2bf(resa);
        if (hasb) {
            float resb = fmaf(dis[n + 1], accb, bv);
            if (RELU) resb = fmaxf(resb, 0.f);
            hout[(size_t)(n + 1) * F + lane] = f2bf(resb);
        }
    }
}

__global__ void k_pool_init(float* __restrict__ out) {
    int i = blockIdx.x * blockDim.x + threadIdx.x;
    if (i < N_GRAPHS * F) out[i] = -INFINITY;
}

__device__ inline void atomicMaxFloat(float* addr, float v) {
    if (v >= 0.f) atomicMax((int*)addr, __float_as_int(v));
    else          atomicMin((unsigned int*)addr, __float_as_uint(v));
}

// batch is sorted: each wave scans a contiguous node chunk, keeps running max,
// flushes on graph boundary.
__global__ __launch_bounds__(256) void k_pool(const ushort* __restrict__ h,
                                              const int* __restrict__ batch,
                                              float* __restrict__ out) {
    int lane = threadIdx.x & 63;
    int wid  = __builtin_amdgcn_readfirstlane((blockIdx.x * blockDim.x + threadIdx.x) >> 6);
    int nwaves = (gridDim.x * blockDim.x) >> 6;
    int per = (N_NODES + nwaves - 1) / nwaves;
    int n0 = wid * per, n1 = min(N_NODES, n0 + per);
    if (n0 >= n1) return;
    float acc = -INFINITY;
    int cur = batch[n0];
    for (int n = n0; n < n1; ++n) {
        int g = batch[n];
        if (g != cur) {
            atomicMaxFloat(&out[cur * F + lane], acc);
            acc = -INFINITY; cur = g;
        }
        acc = fmaxf(acc, bf2f(h[(size_t)n * F + lane]));
    }
    atomicMaxFloat(&out[cur * F + lane], acc);
}

extern "C" void kernel_launch(void* const* d_in, const int* in_sizes, int n_in,
                              void* d_out, int out_size, void* d_ws, size_t ws_size,
                              hipStream_t stream) {
    const float* x     = (const float*)d_in[0];
    const int*   ei    = (const int*)d_in[1];
    const int*   batch = (const int*)d_in[2];
    const float* W1 = (const float*)d_in[3];
    const float* b1 = (const float*)d_in[4];
    const float* W2 = (const float*)d_in[5];
    const float* b2 = (const float*)d_in[6];
    const float* W3 = (const float*)d_in[7];
    const float* b3 = (const float*)d_in[8];
    const int* src = ei;
    const int* dst = ei + N_EDGES;

    char* ws = (char*)d_ws;
    ushort* h      = (ushort*)(ws + OFF_H);
    int*    rank   = (int*)(ws + OFF_H);     // alias: only live during CSR build
    ushort* hw     = (ushort*)(ws + OFF_HW);
    float*  dis    = (float*)(ws + OFF_DIS);
    int*    degcnt = (int*)(ws + OFF_DEG);
    int*    rowptr = (int*)(ws + OFF_ROWP);
    int*    col    = (int*)(ws + OFF_COL);
    int*    bsum   = (int*)(ws + OFF_BSUM);
    float*  out    = (float*)d_out;

    k_zero<<<(N_NODES + 255) / 256, 256, 0, stream>>>(degcnt, N_NODES);
    k_degree<<<(N_EDGES + 255) / 256, 256, 0, stream>>>(dst, degcnt, rank);
    k_scan1<<<98, 1024, 0, stream>>>(degcnt, rowptr, bsum, dis);
    k_scan2<<<1, 64, 0, stream>>>(bsum, 98);
    k_scan3<<<98, 1024, 0, stream>>>(rowptr, bsum);
    k_fill<<<(N_EDGES + 255) / 256, 256, 0, stream>>>(src, dst, rowptr, rank, col);

    const int GEMM_BLOCKS = ((N_NODES + 63) / 64);   // one 4-wave block per 64-row chunk

    // layer 1 (f32 input x)
    k_gemm<float><<<GEMM_BLOCKS, 256, 0, stream>>>(x, W1, dis, hw);
    k_agg<true><<<4096, 256, 0, stream>>>(hw, rowptr, col, dis, b1, h);
    // layer 2 (bf16 h)
    k_gemm<ushort><<<GEMM_BLOCKS, 256, 0, stream>>>(h, W2, dis, hw);
    k_agg<true><<<4096, 256, 0, stream>>>(hw, rowptr, col, dis, b2, h);
    // layer 3
    k_gemm<ushort><<<GEMM_BLOCKS, 256, 0, stream>>>(h, W3, dis, hw);
    k_agg<false><<<4096, 256, 0, stream>>>(hw, rowptr, col, dis, b3, h);

    // global max pool
    k_pool_init<<<(N_GRAPHS * F + 255) / 256, 256, 0, stream>>>(out);
    k_pool<<<512, 256, 0, stream>>>(h, batch, out);
}

// Round 6
// 217.136 us; speedup vs baseline: 2.2000x; 1.0924x over previous
//
#include <hip/hip_runtime.h>
#include <math.h>

#define N_NODES  100000
#define N_EDGES  800000
#define F        64
#define N_GRAPHS 64

typedef _Float16 half8 __attribute__((ext_vector_type(8)));
typedef float    f32x4 __attribute__((ext_vector_type(4)));

// ---------------- workspace layout (bytes) ----------------
#define OFF_BUFA 0u           // ushort[N*F] 12,800,000 (xs / hs ping; rank aliases head)
#define OFF_BUFB 12800000u    // ushort[N*F] 12,800,000
#define OFF_DIS  25600000u    // float[N]       400,000
#define OFF_DEG  26000000u    // int[N]         400,000
#define OFF_ROWP 26400000u    // int[N+1]       400,004 (pad to 64)
#define OFF_COL  26800064u    // int[E]       3,200,000
#define OFF_BSUM 30000064u    // int[128]
#define OFF_WT   30000576u    // _Float16[3*4096] 24,576
// total ~30.0 MB

__device__ inline ushort f2bf(float f) {               // round-to-nearest-even
    uint u = __float_as_uint(f);
    u = (u + 0x7FFFu + ((u >> 16) & 1u)) >> 16;
    return (ushort)u;
}
__device__ inline float bf2f(ushort s) {
    return __uint_as_float(((uint)s) << 16);
}

__global__ void k_zero(int* __restrict__ p, int n) {
    int i = blockIdx.x * blockDim.x + threadIdx.x;
    if (i < n) p[i] = 0;
}

// degree count AND per-edge rank (return value of the atomic we already pay)
__global__ void k_degree(const int* __restrict__ dst, int* __restrict__ degcnt,
                         int* __restrict__ rank) {
    int e = blockIdx.x * blockDim.x + threadIdx.x;
    if (e < N_EDGES) rank[e] = atomicAdd(&degcnt[dst[e]], 1);
}

// block scan of degcnt -> rowptr[i+1]; block totals -> bsum; dis fused.
__global__ void k_scan1(const int* __restrict__ degcnt, int* __restrict__ rowptr,
                        int* __restrict__ bsum, float* __restrict__ dis) {
    __shared__ int s[1024];
    int i = blockIdx.x * 1024 + threadIdx.x;
    int v = (i < N_NODES) ? degcnt[i] : 0;
    if (i < N_NODES) dis[i] = rsqrtf((float)v + 1.0f);
    s[threadIdx.x] = v;
    __syncthreads();
    for (int off = 1; off < 1024; off <<= 1) {
        int t = (threadIdx.x >= off) ? s[threadIdx.x - off] : 0;
        __syncthreads();
        s[threadIdx.x] += t;
        __syncthreads();
    }
    if (i < N_NODES) rowptr[i + 1] = s[threadIdx.x];
    if (threadIdx.x == 1023) bsum[blockIdx.x] = s[1023];
}

// parallel exclusive scan of the 98 block sums (was a 1-thread serial kernel)
__global__ void k_scan2(int* __restrict__ bsum, int nb) {
    __shared__ int s[128];
    int t = threadIdx.x;
    int v = (t < nb) ? bsum[t] : 0;
    s[t] = v;
    __syncthreads();
    for (int off = 1; off < 128; off <<= 1) {
        int u = (t >= off) ? s[t - off] : 0;
        __syncthreads();
        s[t] += u;
        __syncthreads();
    }
    if (t < nb) bsum[t] = s[t] - v;   // exclusive
}

__global__ void k_scan3(int* __restrict__ rowptr, const int* __restrict__ bsum) {
    int i = blockIdx.x * 1024 + threadIdx.x;
    if (i < N_NODES) rowptr[i + 1] += bsum[blockIdx.x];
    if (i == 0) rowptr[0] = 0;
}

// no atomics: position comes from rowptr + precomputed rank
__global__ void k_fill(const int* __restrict__ src, const int* __restrict__ dst,
                       const int* __restrict__ rowptr, const int* __restrict__ rank,
                       int* __restrict__ col) {
    int e = blockIdx.x * blockDim.x + threadIdx.x;
    if (e < N_EDGES) {
        int d = dst[e];
        col[rowptr[d] + rank[e]] = src[e];
    }
}

// xs = bf16(dis * x)  (layer-1 gather source; 8 elems/thread)
__global__ void k_prepx(const float* __restrict__ x, const float* __restrict__ dis,
                        ushort* __restrict__ xs) {
    int t = blockIdx.x * blockDim.x + threadIdx.x;
    if (t < N_NODES * 8) {
        int n = t >> 3;
        float d = dis[n];
        const float4* px = (const float4*)(x + (size_t)t * 8);
        float4 a = px[0], b = px[1];
        ushort o[8] = { f2bf(d*a.x), f2bf(d*a.y), f2bf(d*a.z), f2bf(d*a.w),
                        f2bf(d*b.x), f2bf(d*b.y), f2bf(d*b.z), f2bf(d*b.w) };
        *(uint4*)(xs + (size_t)t * 8) = *(const uint4*)o;
    }
}

// Wt[w][f][k] = f16(W_w[k][f])  — transposed f16 weights for MFMA B-fragments
__global__ void k_prepw(const float* __restrict__ W1, const float* __restrict__ W2,
                        const float* __restrict__ W3, _Float16* __restrict__ Wt) {
    int t = blockIdx.x * blockDim.x + threadIdx.x;
    if (t < 3 * 4096) {
        int wsel = t >> 12, i = t & 4095;
        int k = i >> 6, f = i & 63;
        const float* Ws = (wsel == 0) ? W1 : (wsel == 1) ? W2 : W3;
        Wt[wsel * 4096 + f * 64 + k] = (_Float16)Ws[k * 64 + f];
    }
}

// Fused GCN layer (agg-first, linearity: agg(hW) = agg(h)W):
//   g[n]  = dis[n] * ( hs[n] + sum_{e:dst=n} hs[src] )      (hs pre-scaled by dis)
//   h'[n] = relu( g[n]·W + b )            [RELU]
//   out   = SCALE ? bf16(dis[n]*h'[n]) : bf16(h'[n])        (next layer's hs / final h)
// Block = 64 nodes, 4 waves. Phase1: wave aggregates 16 nodes (8 ILP-pairs) -> LDS g (f16).
// Phase2: wave w computes rows [16w,16w+16) of g·W via 8x mfma_f32_16x16x32_f16
// (B-frags from pre-transposed f16 Wt, held in VGPRs). Phase3: epilogue -> LDS -> coalesced store.
template<bool RELU, bool SCALE>
__global__ __launch_bounds__(256) void k_layer(const ushort* __restrict__ hs,
                                               const int* __restrict__ rowptr,
                                               const int* __restrict__ col,
                                               const float* __restrict__ dis,
                                               const _Float16* __restrict__ Wt,
                                               const float* __restrict__ bias,
                                               ushort* __restrict__ hout) {
    __shared__ _Float16 g[64 * 64];
    int lane = threadIdx.x & 63;
    int w    = __builtin_amdgcn_readfirstlane(threadIdx.x >> 6);
    int chunk = blockIdx.x * 64;

    // ---------- phase 1: aggregate 16 nodes into LDS (f16, dis-scaled) ----------
    int nbase = chunk + w * 16;
    for (int p = 0; p < 8; ++p) {
        int na = nbase + 2 * p, nb = na + 1;
        bool va = na < N_NODES, vb = nb < N_NODES;
        int e0 = va ? rowptr[na] : 0;
        int e1 = va ? rowptr[na + 1] : 0;
        int e2 = vb ? rowptr[nb + 1] : e1;
        float acca = va ? bf2f(hs[(size_t)na * F + lane]) : 0.f;
        float accb = vb ? bf2f(hs[(size_t)nb * F + lane]) : 0.f;
        int ea = e0, eb = e1;
        while (ea + 3 < e1 && eb + 3 < e2) {       // 8 gathers in flight
            int sa0 = col[ea], sa1 = col[ea+1], sa2 = col[ea+2], sa3 = col[ea+3];
            int sb0 = col[eb], sb1 = col[eb+1], sb2 = col[eb+2], sb3 = col[eb+3];
            float va0 = bf2f(hs[(size_t)sa0 * F + lane]);
            float va1 = bf2f(hs[(size_t)sa1 * F + lane]);
            float va2 = bf2f(hs[(size_t)sa2 * F + lane]);
            float va3 = bf2f(hs[(size_t)sa3 * F + lane]);
            float vb0 = bf2f(hs[(size_t)sb0 * F + lane]);
            float vb1 = bf2f(hs[(size_t)sb1 * F + lane]);
            float vb2 = bf2f(hs[(size_t)sb2 * F + lane]);
            float vb3 = bf2f(hs[(size_t)sb3 * F + lane]);
            acca += va0 + va1 + va2 + va3;
            accb += vb0 + vb1 + vb2 + vb3;
            ea += 4; eb += 4;
        }
        for (; ea + 3 < e1; ea += 4) {
            float v0 = bf2f(hs[(size_t)col[ea]   * F + lane]);
            float v1 = bf2f(hs[(size_t)col[ea+1] * F + lane]);
            float v2 = bf2f(hs[(size_t)col[ea+2] * F + lane]);
            float v3 = bf2f(hs[(size_t)col[ea+3] * F + lane]);
            acca += v0 + v1 + v2 + v3;
        }
        for (; ea < e1; ++ea) acca += bf2f(hs[(size_t)col[ea] * F + lane]);
        for (; eb + 3 < e2; eb += 4) {
            float v0 = bf2f(hs[(size_t)col[eb]   * F + lane]);
            float v1 = bf2f(hs[(size_t)col[eb+1] * F + lane]);
            float v2 = bf2f(hs[(size_t)col[eb+2] * F + lane]);
            float v3 = bf2f(hs[(size_t)col[eb+3] * F + lane]);
            accb += v0 + v1 + v2 + v3;
        }
        for (; eb < e2; ++eb) accb += bf2f(hs[(size_t)col[eb] * F + lane]);

        float da = va ? dis[na] : 0.f;
        float db = vb ? dis[nb] : 0.f;
        int row = w * 16 + 2 * p;
        g[row * 64 + lane]       = (_Float16)(da * acca);
        g[(row + 1) * 64 + lane] = (_Float16)(db * accb);
    }
    __syncthreads();

    // ---------- phase 2: C[16x64] = g_strip · W via MFMA ----------
    int l15 = lane & 15, lh = lane >> 4;
    half8 bfrag[2][4];
#pragma unroll
    for (int ks = 0; ks < 2; ++ks)
#pragma unroll
        for (int nt = 0; nt < 4; ++nt)
            bfrag[ks][nt] = *(const half8*)(Wt + (nt * 16 + l15) * 64 + ks * 32 + lh * 8);

    f32x4 acc[4] = {};
#pragma unroll
    for (int ks = 0; ks < 2; ++ks) {
        half8 a = *(const half8*)(&g[(w * 16 + l15) * 64 + ks * 32 + lh * 8]);
#pragma unroll
        for (int nt = 0; nt < 4; ++nt)
            acc[nt] = __builtin_amdgcn_mfma_f32_16x16x32_f16(a, bfrag[ks][nt], acc[nt], 0, 0, 0);
    }

    // ---------- phase 3: epilogue -> LDS (bf16) -> coalesced global ----------
    float bvals[4];
#pragma unroll
    for (int nt = 0; nt < 4; ++nt) bvals[nt] = bias[nt * 16 + l15];
    ushort* gd = (ushort*)g;
#pragma unroll
    for (int r = 0; r < 4; ++r) {
        int row = w * 16 + lh * 4 + r;       // wave touches only its own strip: no barrier needed
        int ng = chunk + row;
        float dr = 1.f;
        if (SCALE) dr = dis[ng < N_NODES ? ng : (N_NODES - 1)];
#pragma unroll
        for (int nt = 0; nt < 4; ++nt) {
            float v = acc[nt][r] + bvals[nt];
            if (RELU) v = fmaxf(v, 0.f);
            if (SCALE) v *= dr;
            gd[row * 64 + nt * 16 + l15] = f2bf(v);
        }
    }
    __syncthreads();
    int nvalid = N_NODES - chunk; if (nvalid > 64) nvalid = 64;
    for (int c = threadIdx.x; c < 64 * 8; c += 256) {   // 16B chunks: 8 per row
        int row = c >> 3;
        if (row < nvalid) {
            uint4 v = *(const uint4*)(gd + row * 64 + (c & 7) * 8);
            *(uint4*)(hout + (size_t)(chunk + row) * F + (c & 7) * 8) = v;
        }
    }
}

__global__ void k_pool_init(float* __restrict__ out) {
    int i = blockIdx.x * blockDim.x + threadIdx.x;
    if (i < N_GRAPHS * F) out[i] = -INFINITY;
}

__device__ inline void atomicMaxFloat(float* addr, float v) {
    if (v >= 0.f) atomicMax((int*)addr, __float_as_int(v));
    else          atomicMin((unsigned int*)addr, __float_as_uint(v));
}

// batch is sorted: each wave scans a contiguous chunk, flushes on boundary.
__global__ __launch_bounds__(256) void k_pool(const ushort* __restrict__ h,
                                              const int* __restrict__ batch,
                                              float* __restrict__ out) {
    int lane = threadIdx.x & 63;
    int wid  = __builtin_amdgcn_readfirstlane((blockIdx.x * blockDim.x + threadIdx.x) >> 6);
    int nwaves = (gridDim.x * blockDim.x) >> 6;
    int per = (N_NODES + nwaves - 1) / nwaves;
    int n0 = wid * per, n1 = min(N_NODES, n0 + per);
    if (n0 >= n1) return;
    float acc = -INFINITY;
    int cur = batch[n0];
    for (int n = n0; n < n1; ++n) {
        int g = batch[n];
        if (g != cur) {
            atomicMaxFloat(&out[cur * F + lane], acc);
            acc = -INFINITY; cur = g;
        }
        acc = fmaxf(acc, bf2f(h[(size_t)n * F + lane]));
    }
    atomicMaxFloat(&out[cur * F + lane], acc);
}

extern "C" void kernel_launch(void* const* d_in, const int* in_sizes, int n_in,
                              void* d_out, int out_size, void* d_ws, size_t ws_size,
                              hipStream_t stream) {
    const float* x     = (const float*)d_in[0];
    const int*   ei    = (const int*)d_in[1];
    const int*   batch = (const int*)d_in[2];
    const float* W1 = (const float*)d_in[3];
    const float* b1 = (const float*)d_in[4];
    const float* W2 = (const float*)d_in[5];
    const float* b2 = (const float*)d_in[6];
    const float* W3 = (const float*)d_in[7];
    const float* b3 = (const float*)d_in[8];
    const int* src = ei;
    const int* dst = ei + N_EDGES;

    char* ws = (char*)d_ws;
    ushort*   bufA   = (ushort*)(ws + OFF_BUFA);
    int*      rank   = (int*)(ws + OFF_BUFA);     // alias: live only during CSR build
    ushort*   bufB   = (ushort*)(ws + OFF_BUFB);
    float*    dis    = (float*)(ws + OFF_DIS);
    int*      degcnt = (int*)(ws + OFF_DEG);
    int*      rowptr = (int*)(ws + OFF_ROWP);
    int*      col    = (int*)(ws + OFF_COL);
    int*      bsum   = (int*)(ws + OFF_BSUM);
    _Float16* wt     = (_Float16*)(ws + OFF_WT);
    float*    out    = (float*)d_out;

    // CSR build
    k_zero<<<(N_NODES + 255) / 256, 256, 0, stream>>>(degcnt, N_NODES);
    k_degree<<<(N_EDGES + 255) / 256, 256, 0, stream>>>(dst, degcnt, rank);
    k_scan1<<<98, 1024, 0, stream>>>(degcnt, rowptr, bsum, dis);
    k_scan2<<<1, 128, 0, stream>>>(bsum, 98);
    k_scan3<<<98, 1024, 0, stream>>>(rowptr, bsum);
    k_fill<<<(N_EDGES + 255) / 256, 256, 0, stream>>>(src, dst, rowptr, rank, col);

    // prep: xs = bf16(dis*x) (overwrites rank region), Wt = f16 transposed weights
    k_prepx<<<(N_NODES * 8 + 255) / 256, 256, 0, stream>>>(x, dis, bufA);
    k_prepw<<<48, 256, 0, stream>>>(W1, W2, W3, wt);

    const int LBLOCKS = (N_NODES + 63) / 64;   // 1563
    k_layer<true,  true ><<<LBLOCKS, 256, 0, stream>>>(bufA, rowptr, col, dis, wt,        b1, bufB);
    k_layer<true,  true ><<<LBLOCKS, 256, 0, stream>>>(bufB, rowptr, col, dis, wt + 4096, b2, bufA);
    k_layer<false, false><<<LBLOCKS, 256, 0, stream>>>(bufA, rowptr, col, dis, wt + 8192, b3, bufB);

    // global max pool
    k_pool_init<<<(N_GRAPHS * F + 255) / 256, 256, 0, stream>>>(out);
    k_pool<<<512, 256, 0, stream>>>(bufB, batch, out);
}